// Round 10
// baseline (3977.568 us; speedup 1.0000x reference)
//
#include <hip/hip_runtime.h>

#define B_ 8
#define T_ 1024
#define C_ 768
#define H_ 12
#define L_ 12
#define V_ 50257

typedef __bf16 bf16_t;
typedef __bf16 bf16x8 __attribute__((ext_vector_type(8)));
typedef __bf16 bf16x4 __attribute__((ext_vector_type(4)));
typedef float f32x4 __attribute__((ext_vector_type(4)));

#define AS1 __attribute__((address_space(1)))
#define AS3 __attribute__((address_space(3)))

__device__ __forceinline__ unsigned short f2bf(float f) {
  bf16_t h = (bf16_t)f;
  return __builtin_bit_cast(unsigned short, h);
}

__device__ __forceinline__ unsigned short bfbits(bf16_t h) {
  return __builtin_bit_cast(unsigned short, h);
}

// fast gelu: 0.5x(1+erf(x/sqrt2)), erf via Abramowitz-Stegun 7.1.26 (max err 1.5e-7)
__device__ __forceinline__ float fast_gelu(float v) {
  const float xe = v * 0.70710678118f;
  const float ax = fabsf(xe);
  const float t = 1.0f / fmaf(0.3275911f, ax, 1.0f);
  float poly = fmaf(t, 1.061405429f, -1.453152027f);
  poly = fmaf(t, poly, 1.421413741f);
  poly = fmaf(t, poly, -0.284496736f);
  poly = fmaf(t, poly, 0.254829592f);
  poly *= t;
  float er = 1.0f - poly * __expf(-ax * ax);
  er = (xe < 0.0f) ? -er : er;
  return 0.5f * v * (1.0f + er);
}

// ---- DPP 16-lane reductions ----
template<int CTRL>
__device__ __forceinline__ float dppf(float x) {
  return __builtin_bit_cast(float, __builtin_amdgcn_update_dpp(
      0, __builtin_bit_cast(int, x), CTRL, 0xF, 0xF, true));
}
__device__ __forceinline__ float red16_max(float x) {
  x = fmaxf(x, dppf<0xB1>(x));
  x = fmaxf(x, dppf<0x4E>(x));
  x = fmaxf(x, dppf<0x124>(x));
  x = fmaxf(x, dppf<0x128>(x));
  return x;
}
__device__ __forceinline__ float red16_sum(float x) {
  x += dppf<0xB1>(x);
  x += dppf<0x4E>(x);
  x += dppf<0x124>(x);
  x += dppf<0x128>(x);
  return x;
}

// ---------------- embedding ----------------
__global__ __launch_bounds__(192) void embed_kernel(
    const int* __restrict__ idx, const float* __restrict__ wte,
    const float* __restrict__ wpe, float* __restrict__ xf)
{
  const int bt = blockIdx.x;
  const int t = bt & (T_ - 1);
  const int tok = idx[bt];
  const int c4 = threadIdx.x << 2;
  float4 a = *(const float4*)(wte + (size_t)tok * C_ + c4);
  float4 p = *(const float4*)(wpe + (size_t)t * C_ + c4);
  float4 r; r.x = a.x + p.x; r.y = a.y + p.y; r.z = a.z + p.z; r.w = a.w + p.w;
  *(float4*)(xf + (size_t)bt * C_ + c4) = r;
}

// ---------------- layernorm ----------------
template<bool LAST>
__global__ __launch_bounds__(256) void ln_kernel(
    const float* __restrict__ x, const float* __restrict__ gw,
    const float* __restrict__ bw, unsigned short* __restrict__ obf,
    float* __restrict__ of)
{
  __shared__ float red[8];
  const size_t row = LAST ? ((size_t)blockIdx.x * T_ + (T_ - 1)) : (size_t)blockIdx.x;
  const float* xr = x + row * C_;
  const int t = threadIdx.x;
  float v0 = xr[t], v1 = xr[t + 256], v2 = xr[t + 512];
  float s = v0 + v1 + v2;
  #pragma unroll
  for (int off = 32; off; off >>= 1) s += __shfl_xor(s, off);
  if ((t & 63) == 0) red[t >> 6] = s;
  __syncthreads();
  const float mean = (red[0] + red[1] + red[2] + red[3]) * (1.0f / C_);
  const float d0 = v0 - mean, d1 = v1 - mean, d2 = v2 - mean;
  float ss = d0 * d0 + d1 * d1 + d2 * d2;
  #pragma unroll
  for (int off = 32; off; off >>= 1) ss += __shfl_xor(ss, off);
  if ((t & 63) == 0) red[4 + (t >> 6)] = ss;
  __syncthreads();
  const float var = (red[4] + red[5] + red[6] + red[7]) * (1.0f / C_);
  const float rs = rsqrtf(var + 1e-5f);
  float o0 = d0 * rs * gw[t] + bw[t];
  float o1 = d1 * rs * gw[t + 256] + bw[t + 256];
  float o2 = d2 * rs * gw[t + 512] + bw[t + 512];
  if (LAST) {
    float* orow = of + (size_t)blockIdx.x * C_;
    orow[t] = o0; orow[t + 256] = o1; orow[t + 512] = o2;
  } else {
    unsigned short* orow = obf + row * C_;
    orow[t] = f2bf(o0); orow[t + 256] = f2bf(o1); orow[t + 512] = f2bf(o2);
  }
}

// ---------------- fused weight convert ----------------
__global__ __launch_bounds__(256) void cvtw4_kernel(
    const float* __restrict__ wq, const float* __restrict__ wa,
    const float* __restrict__ wf, const float* __restrict__ wm,
    unsigned short* __restrict__ out)
{
  __shared__ float tile[32][33];
  const int i = blockIdx.x;
  const float* W; unsigned short* Wt; int K, N, tix;
  if (i < 1728)      { W = wq; Wt = out;                 K = C_;     N = 3 * C_; tix = i; }
  else if (i < 2304) { W = wa; Wt = out + 3 * C_ * C_;   K = C_;     N = C_;     tix = i - 1728; }
  else if (i < 4608) { W = wf; Wt = out + 4 * C_ * C_;   K = C_;     N = 4 * C_; tix = i - 2304; }
  else               { W = wm; Wt = out + 8 * C_ * C_;   K = 4 * C_; N = C_;     tix = i - 4608; }
  const int ntx = N >> 5;
  const int kb = (tix / ntx) << 5, nb = (tix % ntx) << 5;
  const int t = threadIdx.x;
  {
    const int k = t >> 3, n4 = (t & 7) << 2;
    float4 v = *(const float4*)(W + (size_t)(kb + k) * N + nb + n4);
    tile[k][n4] = v.x; tile[k][n4 + 1] = v.y; tile[k][n4 + 2] = v.z; tile[k][n4 + 3] = v.w;
  }
  __syncthreads();
  {
    const int n = t >> 3, k4 = (t & 7) << 2;
    ushort4 o;
    o.x = f2bf(tile[k4][n]);     o.y = f2bf(tile[k4 + 1][n]);
    o.z = f2bf(tile[k4 + 2][n]); o.w = f2bf(tile[k4 + 3][n]);
    *(ushort4*)(Wt + (size_t)(nb + n) * K + kb + k4) = o;
  }
}

// ---------------- GEMM 256x256 v3: burst-stage + 4-phase interleave ----------------
// 512 thr = 8 waves (2M x 4N), per-wave 128x64 (8x4 frags), BK=64, 1 block/CU.
// P0: stage ALL 8 loads of tile t+1; vmcnt(8); barrier; 12 ds_read; lgkm0; 16 MFMA.
// P1/P2: ds_read BEFORE barrier (overlaps other waves' MFMA); P3 register-only.
// EPI 2: gelu->bf16. EPI 3: qkv split->bf16 [b,h,t,d].
template<int EPI>
__global__ __launch_bounds__(512, 1) void gemm256(
    const unsigned short* __restrict__ A, const unsigned short* __restrict__ Bt,
    const float* __restrict__ bias, unsigned short* __restrict__ Cb,
    int N, int K, int nx)
{
  __shared__ __align__(16) unsigned short As[2][2][128 * 64];
  __shared__ __align__(16) unsigned short Bs[2][2][128 * 64];
  const int tid = threadIdx.x;
  const int lane = tid & 63;
  const int w = tid >> 6;            // 0..7
  const int wr = w >> 2;             // 0..1 : A-half (128-row band)
  const int wc = w & 3;              // 0..3 : 64-col band of B
  const int l15 = lane & 15, l4 = lane >> 4;
  const int s7 = l15 & 7;

  // XCD mapping: xcd owns 4 m-panels, n-fastest
  const int bid = blockIdx.x;
  const int xcd = bid & 7;
  const int j = bid >> 3;
  const int mblk = xcd * 4 + j / nx;
  const int nblk = j - (j / nx) * nx;
  const int m0 = mblk * 256, n0 = nblk * 256;

  f32x4 acc[8][4] = {};

  const int srow8 = lane >> 3;            // 0..7
  const int sch = (lane & 7) ^ srow8;     // pre-swizzled 16B chunk (involution)

  // stage whole K-tile (A both halves + B both halves): 8 loads/thread
  auto stage = [&](int kt, int q) {
    const size_t k0 = (size_t)kt * 64;
    #pragma unroll
    for (int h = 0; h < 2; ++h)
      #pragma unroll
      for (int jj = 0; jj < 2; ++jj)
        __builtin_amdgcn_global_load_lds(
            (const AS1 unsigned int*)(A + (size_t)(m0 + h * 128 + jj * 64 + w * 8 + srow8) * K + sch * 8 + k0),
            (AS3 unsigned int*)(&As[q][h][(jj * 8 + w) * 512]), 16, 0, 0);
    #pragma unroll
    for (int h = 0; h < 2; ++h)
      #pragma unroll
      for (int jj = 0; jj < 2; ++jj)
        __builtin_amdgcn_global_load_lds(
            (const AS1 unsigned int*)(Bt + (size_t)(n0 + h * 128 + jj * 64 + w * 8 + srow8) * K + sch * 8 + k0),
            (AS3 unsigned int*)(&Bs[q][h][(jj * 8 + w) * 512]), 16, 0, 0);
  };

  const int nk = K >> 6;
  stage(0, 0);

  for (int t = 0; t < nk; ++t) {
    const int p = t & 1, q = p ^ 1;
    bf16x8 Af[4][2], B01[2][2], B23[2][2];
    auto rdA = [&](int f, int ks) -> bf16x8 {
      return *(const bf16x8*)(&As[p][wr][(f * 16 + l15) * 64 + ((((ks << 2) | l4) ^ s7) << 3)]);
    };
    auto rdB = [&](int nf, int ks) -> bf16x8 {
      return *(const bf16x8*)(&Bs[p][wc >> 1][((wc & 1) * 64 + nf * 16 + l15) * 64 + ((((ks << 2) | l4) ^ s7) << 3)]);
    };

    // ---- P0: burst-stage tile t+1; vmcnt(8); barrier; read A0-3,B0-1; MFMA ----
    if (t + 1 < nk) {
      stage(t + 1, q);
      asm volatile("s_waitcnt vmcnt(8)" ::: "memory");
    } else {
      asm volatile("s_waitcnt vmcnt(0)" ::: "memory");
    }
    __builtin_amdgcn_s_barrier();
    #pragma unroll
    for (int f = 0; f < 4; ++f) { Af[f][0] = rdA(f, 0); Af[f][1] = rdA(f, 1); }
    #pragma unroll
    for (int nf = 0; nf < 2; ++nf) { B01[nf][0] = rdB(nf, 0); B01[nf][1] = rdB(nf, 1); }
    asm volatile("s_waitcnt lgkmcnt(0)" ::: "memory");
    __builtin_amdgcn_sched_barrier(0);
    __builtin_amdgcn_s_setprio(1);
    #pragma unroll
    for (int f = 0; f < 4; ++f)
      #pragma unroll
      for (int nf = 0; nf < 2; ++nf)
        #pragma unroll
        for (int ks = 0; ks < 2; ++ks)
          acc[f][nf] = __builtin_amdgcn_mfma_f32_16x16x32_bf16(Af[f][ks], B01[nf][ks], acc[f][nf], 0, 0, 0);
    __builtin_amdgcn_s_setprio(0);

    // ---- P1: read B2-3 (before barrier); MFMA A0-3 x B2-3 ----
    #pragma unroll
    for (int nf = 0; nf < 2; ++nf) { B23[nf][0] = rdB(nf + 2, 0); B23[nf][1] = rdB(nf + 2, 1); }
    __builtin_amdgcn_s_barrier();
    asm volatile("s_waitcnt lgkmcnt(0)" ::: "memory");
    __builtin_amdgcn_sched_barrier(0);
    __builtin_amdgcn_s_setprio(1);
    #pragma unroll
    for (int f = 0; f < 4; ++f)
      #pragma unroll
      for (int nf = 0; nf < 2; ++nf)
        #pragma unroll
        for (int ks = 0; ks < 2; ++ks)
          acc[f][nf + 2] = __builtin_amdgcn_mfma_f32_16x16x32_bf16(Af[f][ks], B23[nf][ks], acc[f][nf + 2], 0, 0, 0);
    __builtin_amdgcn_s_setprio(0);

    // ---- P2: read A4-7 (before barrier); MFMA A4-7 x B2-3 ----
    #pragma unroll
    for (int f = 0; f < 4; ++f) { Af[f][0] = rdA(f + 4, 0); Af[f][1] = rdA(f + 4, 1); }
    __builtin_amdgcn_s_barrier();
    asm volatile("s_waitcnt lgkmcnt(0)" ::: "memory");
    __builtin_amdgcn_sched_barrier(0);
    __builtin_amdgcn_s_setprio(1);
    #pragma unroll
    for (int f = 0; f < 4; ++f)
      #pragma unroll
      for (int nf = 0; nf < 2; ++nf)
        #pragma unroll
        for (int ks = 0; ks < 2; ++ks)
          acc[f + 4][nf + 2] = __builtin_amdgcn_mfma_f32_16x16x32_bf16(Af[f][ks], B23[nf][ks], acc[f + 4][nf + 2], 0, 0, 0);
    __builtin_amdgcn_s_setprio(0);

    // ---- P3: register-only; MFMA A4-7 x B0-1 (B01 kept live) ----
    __builtin_amdgcn_s_barrier();
    __builtin_amdgcn_s_setprio(1);
    #pragma unroll
    for (int f = 0; f < 4; ++f)
      #pragma unroll
      for (int nf = 0; nf < 2; ++nf)
        #pragma unroll
        for (int ks = 0; ks < 2; ++ks)
          acc[f + 4][nf] = __builtin_amdgcn_mfma_f32_16x16x32_bf16(Af[f][ks], B01[nf][ks], acc[f + 4][nf], 0, 0, 0);
    __builtin_amdgcn_s_setprio(0);
  }

  #pragma unroll
  for (int f = 0; f < 8; ++f) {
    #pragma unroll
    for (int nf = 0; nf < 4; ++nf) {
      const int col = n0 + wc * 64 + nf * 16 + l15;
      const float bv = bias[col];
      int hh = 0, dd = 0;
      unsigned short* qkvo = nullptr;
      if constexpr (EPI == 3) {
        const int which = col / C_;
        const int rem = col - which * C_;
        hh = rem >> 6; dd = rem & 63;
        qkvo = Cb + (size_t)which * ((size_t)B_ * H_ * T_ * 64);
      }
      #pragma unroll
      for (int i = 0; i < 4; ++i) {
        const int row = m0 + wr * 128 + f * 16 + l4 * 4 + i;
        float v = acc[f][nf][i] + bv;
        if constexpr (EPI == 2) {
          Cb[(size_t)row * N + col] = f2bf(fast_gelu(v));
        } else {
          const int bb = row >> 10, tt = row & (T_ - 1);
          qkvo[(((size_t)bb * H_ + hh) * T_ + tt) * 64 + dd] = f2bf(v);
        }
      }
    }
  }
}

// ---------------- GEMM 128x128 (ao/mo): counted-vmcnt dbuf (r6 config) ----------------
template<int EPI>
__global__ __launch_bounds__(256, 2) void gemm_bt(
    const unsigned short* __restrict__ A, const unsigned short* __restrict__ Bt,
    const float* __restrict__ bias, float* __restrict__ Cf,
    unsigned short* __restrict__ Cb, int M, int N, int K, int nx)
{
  (void)M; (void)nx;
  __shared__ unsigned short As[2][128 * 64];
  __shared__ unsigned short Bs[2][128 * 64];
  const int tid = threadIdx.x;
  const int lane = tid & 63;
  const int w = tid >> 6;
  const int wr = w >> 1, wc = w & 1;
  const int l15 = lane & 15, l4 = lane >> 4;
  const int swz = lane & 7;

  const int bid = blockIdx.x;
  const int xcd = bid & 7;
  const int j = bid >> 3;
  const int mblk = xcd * 8 + (j & 7);
  const int nblk = j >> 3;
  const int m0 = mblk * 128, n0 = nblk * 128;

  f32x4 acc[4][4] = {};

  const int srow = lane >> 3;
  const int schunk = (lane & 7) ^ srow;
  const unsigned short* aSrc = A + (size_t)(m0 + w * 32 + srow) * K + schunk * 8;
  const unsigned short* bSrc = Bt + (size_t)(n0 + w * 32 + srow) * K + schunk * 8;
  const int ldsRowBase = (w * 32) * 64;

  auto stage = [&](int kt, int p) {
    const int k0 = kt << 6;
    #pragma unroll
    for (int jj = 0; jj < 4; ++jj)
      __builtin_amdgcn_global_load_lds(
          (const AS1 unsigned int*)(aSrc + (size_t)jj * 8 * K + k0),
          (AS3 unsigned int*)(&As[p][ldsRowBase + jj * 8 * 64]), 16, 0, 0);
    #pragma unroll
    for (int jj = 0; jj < 4; ++jj)
      __builtin_amdgcn_global_load_lds(
          (const AS1 unsigned int*)(bSrc + (size_t)jj * 8 * K + k0),
          (AS3 unsigned int*)(&Bs[p][ldsRowBase + jj * 8 * 64]), 16, 0, 0);
  };

  auto compute = [&](int p) {
    const unsigned short* aw = &As[p][(wr * 64) * 64];
    const unsigned short* bw2 = &Bs[p][(wc * 64) * 64];
    #pragma unroll
    for (int ks = 0; ks < 2; ++ks) {
      bf16x8 af[4], bf[4];
      #pragma unroll
      for (int mf = 0; mf < 4; ++mf)
        af[mf] = *(const bf16x8*)(aw + (mf * 16 + l15) * 64 + (((ks << 2) | l4) ^ swz) * 8);
      #pragma unroll
      for (int nf = 0; nf < 4; ++nf)
        bf[nf] = *(const bf16x8*)(bw2 + (nf * 16 + l15) * 64 + (((ks << 2) | l4) ^ swz) * 8);
      __builtin_amdgcn_s_setprio(1);
      #pragma unroll
      for (int mf = 0; mf < 4; ++mf)
        #pragma unroll
        for (int nf = 0; nf < 4; ++nf)
          acc[mf][nf] = __builtin_amdgcn_mfma_f32_16x16x32_bf16(af[mf], bf[nf], acc[mf][nf], 0, 0, 0);
      __builtin_amdgcn_s_setprio(0);
    }
  };

  const int nk = K >> 6;
  stage(0, 0);
  for (int kt = 0; kt < nk - 1; ++kt) {
    const int p = kt & 1;
    stage(kt + 1, p ^ 1);
    asm volatile("s_waitcnt vmcnt(8)" ::: "memory");
    __builtin_amdgcn_s_barrier();
    compute(p);
    __builtin_amdgcn_s_barrier();
  }
  asm volatile("s_waitcnt vmcnt(0)" ::: "memory");
  __builtin_amdgcn_s_barrier();
  compute((nk - 1) & 1);

  #pragma unroll
  for (int mf = 0; mf < 4; ++mf) {
    #pragma unroll
    for (int nf = 0; nf < 4; ++nf) {
      const int col = n0 + wc * 64 + nf * 16 + l15;
      const float bv = bias[col];
      #pragma unroll
      for (int i = 0; i < 4; ++i) {
        const int row = m0 + wr * 64 + mf * 16 + l4 * 4 + i;
        float v = acc[mf][nf][i] + bv;
        if constexpr (EPI == 1) {
          Cf[(size_t)row * N + col] += v;
        } else if constexpr (EPI == 2) {
          Cb[(size_t)row * N + col] = f2bf(fast_gelu(v));
        }
      }
    }
  }
}

// ---------------- flash attention v5 (r9: dual-band balance + defer-max) ----------------
__global__ __launch_bounds__(256) void attn_kernel(
    const unsigned short* __restrict__ Qb, const unsigned short* __restrict__ Kb,
    const unsigned short* __restrict__ Vb, unsigned short* __restrict__ y)
{
  const int pb = blockIdx.x / 96;
  const int bh = blockIdx.x % 96;
  const int h = bh % H_;
  const int b = bh / H_;
  const int tid = threadIdx.x, lane = tid & 63, w = tid >> 6;
  const int l15 = lane & 15, l4 = lane >> 4;

  const int qband0 = pb * 64 + w * 16;
  const int qband1 = (15 - pb) * 64 + w * 16;
  const int NT = (17 - pb) >> 1;

  __shared__ unsigned short Ks[128 * 64];
  __shared__ unsigned short Vt[64 * 136];
  __shared__ unsigned short Pb[4][32 * 74];

  bf16x8 qf[2][2];
  {
    const unsigned short* q0p = Qb + ((size_t)bh * T_ + qband0) * 64;
    const unsigned short* q1p = Qb + ((size_t)bh * T_ + qband1) * 64;
    #pragma unroll
    for (int ks = 0; ks < 2; ++ks) {
      qf[0][ks] = *(const bf16x8*)(q0p + l15 * 64 + ks * 32 + l4 * 8);
      qf[1][ks] = *(const bf16x8*)(q1p + l15 * 64 + ks * 32 + l4 * 8);
    }
  }

  f32x4 o[2][4] = {};
  float mrow[2][4], lrow[2][4];
  #pragma unroll
  for (int mf = 0; mf < 2; ++mf)
    #pragma unroll
    for (int i = 0; i < 4; ++i) { mrow[mf][i] = -1e30f; lrow[mf][i] = 0.0f; }

  const unsigned short* kb0 = Kb + (size_t)bh * T_ * 64;
  const unsigned short* vb0 = Vb + (size_t)bh * T_ * 64;
  const int ck = w;
  const int skey = lane;
  const int sw = (skey & 7);

  bf16x8 kr0, kr1, kr2, kr3, vr0, vr1, vr2, vr3;
  {
    const unsigned short* kp = kb0 + (size_t)skey * 64;
    const unsigned short* vp = vb0 + (size_t)skey * 64;
    kr0 = *(const bf16x8*)(kp + ck * 8);
    kr1 = *(const bf16x8*)(kp + (ck + 4) * 8);
    kr2 = *(const bf16x8*)(kp + 64 * 64 + ck * 8);
    kr3 = *(const bf16x8*)(kp + 64 * 64 + (ck + 4) * 8);
    vr0 = *(const bf16x8*)(vp + ck * 8);
    vr1 = *(const bf16x8*)(vp + (ck + 4) * 8);
    vr2 = *(const bf16x8*)(vp + 64 * 64 + ck * 8);
    vr3 = *(const bf16x8*)(vp + 64 * 64 + (ck + 4) * 8);
  }

  for (int kt = 0; kt < NT; ++kt) {
    const int k0 = kt << 7;
    __syncthreads();
    *(bf16x8*)(Ks + skey * 64 + ((ck ^ sw) * 8)) = kr0;
    *(bf16x8*)(Ks + skey * 64 + (((ck + 4) ^ sw) * 8)) = kr1;
    *(bf16x8*)(Ks + (skey + 64) * 64 + ((ck ^ sw) * 8)) = kr2;
    *(bf16x8*)(Ks + (skey + 64) * 64 + (((ck + 4) ^ sw) * 8)) = kr3;
    #pragma unroll
    for (int jj = 0; jj < 8; ++jj) {
      Vt[(ck * 8 + jj) * 136 + skey]            = bfbits(vr0[jj]);
      Vt[((ck + 4) * 8 + jj) * 136 + skey]      = bfbits(vr1[jj]);
      Vt[(ck * 8 + jj) * 136 + skey + 64]       = bfbits(vr2[jj]);
      Vt[((ck + 4) * 8 + jj) * 136 + skey + 64] = bfbits(vr3[jj]);
    }
    __syncthreads();
    if (kt + 1 < NT) {
      const int kn = (kt + 1) << 7;
      const unsigned short* kp = kb0 + (size_t)(kn + skey) * 64;
      const unsigned short* vp = vb0 + (size_t)(kn + skey) * 64;
      kr0 = *(const bf16x8*)(kp + ck * 8);
      kr1 = *(const bf16x8*)(kp + (ck + 4) * 8);
      kr2 = *(const bf16x8*)(kp + 64 * 64 + ck * 8);
      kr3 = *(const bf16x8*)(kp + 64 * 64 + (ck + 4) * 8);
      vr0 = *(const bf16x8*)(vp + ck * 8);
      vr1 = *(const bf16x8*)(vp + (ck + 4) * 8);
      vr2 = *(const bf16x8*)(vp + 64 * 64 + ck * 8);
      vr3 = *(const bf16x8*)(vp + 64 * 64 + (ck + 4) * 8);
    }

    #pragma unroll
    for (int h2 = 0; h2 < 2; ++h2) {
      const int kh0 = k0 + h2 * 64;
      const bool act0 = (kh0 <= qband0 + 15);
      const bool act1 = (kh0 <= qband1 + 15);
      if (!act0 && !act1) continue;

      f32x4 s[2][4] = {};
      __builtin_amdgcn_s_setprio(1);
      #pragma unroll
      for (int ks = 0; ks < 2; ++ks) {
        #pragma unroll
        for (int nfk = 0; nfk < 4; ++nfk) {
          const int key = h2 * 64 + nfk * 16 + l15;
          bf16x8 kf = *(const bf16x8*)(Ks + key * 64 + ((((ks << 2) | l4) ^ (l15 & 7)) * 8));
          if (act0) s[0][nfk] = __builtin_amdgcn_mfma_f32_16x16x32_bf16(qf[0][ks], kf, s[0][nfk], 0, 0, 0);
          if (act1) s[1][nfk] = __builtin_amdgcn_mfma_f32_16x16x32_bf16(qf[1][ks], kf, s[1][nfk], 0, 0, 0);
        }
      }
      __builtin_amdgcn_s_setprio(0);

      #pragma unroll
      for (int mf = 0; mf < 2; ++mf) {
        const bool act = mf ? act1 : act0;
        if (!act) continue;
        const int qb0 = mf ? qband1 : qband0;
        const int qrow = qb0 + l4 * 4;
        const bool fullt = (kh0 + 63) <= qb0;
        float pvv[4][4], tm[4];
        #pragma unroll
        for (int i = 0; i < 4; ++i) {
          const int q = qrow + i;
          float m_ = -1e30f;
          #pragma unroll
          for (int nfk = 0; nfk < 4; ++nfk) {
            float x = s[mf][nfk][i] * 0.125f;
            x = fullt ? x : ((kh0 + nfk * 16 + l15 <= q) ? x : -1e30f);
            pvv[nfk][i] = x;
            m_ = fmaxf(m_, x);
          }
          tm[i] = red16_max(m_);
        }
        bool need = false;
        #pragma unroll
        for (int i = 0; i < 4; ++i) need |= (tm[i] > mrow[mf][i] + 8.0f);
        if (__any(need)) {
          #pragma unroll
          for (int i = 0; i < 4; ++i) {
            const float mnew = fmaxf(mrow[mf][i], tm[i]);
            const float alpha = __expf(mrow[mf][i] - mnew);
            mrow[mf][i] = mnew;
            lrow[mf][i] *= alpha;
            #pragma unroll
            for (int nf = 0; nf < 4; ++nf) o[mf][nf][i] *= alpha;
          }
        }
        #pragma unroll
        for (int i = 0; i < 4; ++i) {
          float rsum = 0.0f;
          #pragma unroll
          for (int nfk = 0; nfk < 4; ++nfk) {
            const float p = __expf(pvv[nfk][i] - mrow[mf][i]);
            pvv[nfk][i] = p; rsum += p;
          }
          rsum = red16_sum(rsum);
          lrow[mf][i] += rsum;
        }
        #pragma unroll
        for (int nfk = 0; nfk < 4; ++nfk)
          #pragma unroll
          for (int i = 0; i < 4; ++i)
            Pb[w][(mf * 16 + l4 * 4 + i) * 74 + nfk * 16 + l15] = f2bf(pvv[nfk][i]);
      }

      bf16x8 pa[2][2];
      #pragma unroll
      for (int mf = 0; mf < 2; ++mf)
        if (mf ? act1 : act0)
          #pragma unroll
          for (int k2 = 0; k2 < 2; ++k2)
            pa[mf][k2] = *(const bf16x8*)(Pb[w] + (mf * 16 + l15) * 74 + k2 * 32 + l4 * 8);
      __builtin_amdgcn_s_setprio(1);
      #pragma unroll
      for (int nf = 0; nf < 4; ++nf) {
        const int d = nf * 16 + l15;
        #pragma unroll
        for (int k2 = 0; k2 < 2; ++k2) {
          bf16x8 vf = *(const bf16x8*)(Vt + d * 136 + h2 * 64 + k2 * 32 + l4 * 8);
          if (act0) o[0][nf] = __builtin_amdgcn_mfma_f32_16x16x32_bf16(pa[0][k2], vf, o[0][nf], 0, 0, 0);
          if (act1) o[1][nf] = __builtin_amdgcn_mfma_f32_16x16x32_bf16(pa[1][k2], vf, o[1][nf], 0, 0, 0);
        }
      }
      __builtin_amdgcn_s_setprio(0);
    }
  }

  #pragma unroll
  for (int mf = 0; mf < 2; ++mf) {
    const int qb0 = mf ? qband1 : qband0;
    #pragma unroll
    for (int i = 0; i < 4; ++i) {
      const float inv = 1.0f / lrow[mf][i];
      const int q = qb0 + l4 * 4 + i;
      unsigned short* yr = y + (size_t)(b * T_ + q) * C_ + h * 64;
      #pragma unroll
      for (int nf = 0; nf < 4; ++nf)
        yr[nf * 16 + l15] = f2bf(o[mf][nf][i] * inv);
    }
  }
}

// ---------------- head ----------------
__global__ __launch_bounds__(256) void head_kernel(
    const float* __restrict__ lnf, const float* __restrict__ wte,
    float* __restrict__ out)
{
  __shared__ float xs[B_ * C_];
  for (int i = threadIdx.x; i < B_ * C_; i += 256) xs[i] = lnf[i];
  __syncthreads();
  const int w = threadIdx.x >> 6, lane = threadIdx.x & 63;
  const int v = blockIdx.x * 4 + w;
  if (v >= V_) return;
  const float* wv = wte + (size_t)v * C_ + lane * 12;
  float4 w0 = *(const float4*)(wv);
  float4 w1 = *(const float4*)(wv + 4);
  float4 w2 = *(const float4*)(wv + 8);
  float acc[B_];
  #pragma unroll
  for (int bb = 0; bb < B_; ++bb) {
    const float* xr = xs + bb * C_ + lane * 12;
    float4 x0 = *(const float4*)(xr);
    float4 x1 = *(const float4*)(xr + 4);
    float4 x2 = *(const float4*)(xr + 8);
    acc[bb] = w0.x * x0.x + w0.y * x0.y + w0.z * x0.z + w0.w * x0.w
            + w1.x * x1.x + w1.y * x1.y + w1.z * x1.z + w1.w * x1.w
            + w2.x * x2.x + w2.y * x2.y + w2.z * x2.z + w2.w * x2.w;
  }
  #pragma unroll
  for (int off = 32; off; off >>= 1) {
    #pragma unroll
    for (int bb = 0; bb < B_; ++bb)
      acc[bb] += __shfl_xor(acc[bb], off);
  }
  if (lane == 0) {
    #pragma unroll
    for (int bb = 0; bb < B_; ++bb)
      out[(size_t)bb * V_ + v] = acc[bb];
  }
}

// ---------------- launcher ----------------
extern "C" void kernel_launch(void* const* d_in, const int* in_sizes, int n_in,
                              void* d_out, int out_size, void* d_ws, size_t ws_size,
                              hipStream_t stream)
{
  (void)in_sizes; (void)n_in; (void)out_size; (void)ws_size;
  const int*   idx   = (const int*)d_in[0];
  const float* wte   = (const float*)d_in[1];
  const float* wpe   = (const float*)d_in[2];
  const float* ln1_g = (const float*)d_in[3];
  const float* ln1_b = (const float*)d_in[4];
  const float* w_qkv = (const float*)d_in[5];
  const float* b_qkv = (const float*)d_in[6];
  const float* w_ao  = (const float*)d_in[7];
  const float* b_ao  = (const float*)d_in[8];
  const float* ln2_g = (const float*)d_in[9];
  const float* ln2_b = (const float*)d_in[10];
  const float* w_fc  = (const float*)d_in[11];
  const float* b_fc  = (const float*)d_in[12];
  const float* w_mo  = (const float*)d_in[13];
  const float* b_mo  = (const float*)d_in[14];
  const float* lnf_g = (const float*)d_in[15];
  const float* lnf_b = (const float*)d_in[16];

  char* ws = (char*)d_ws;
  size_t off = 0;
  auto wsalloc = [&](size_t bytes) -> void* {
    void* p = ws + off;
    off += (bytes + 255) & ~(size_t)255;
    return p;
  };
  const size_t SZH = (size_t)B_ * H_ * T_ * 64;
  float* xf             = (float*)wsalloc((size_t)B_ * T_ * C_ * 4);
  unsigned short* qkv3  = (unsigned short*)wsalloc(3 * SZH * 2);
  unsigned short* a_in  = (unsigned short*)wsalloc((size_t)B_ * T_ * C_ * 2);
  unsigned short* act2  = (unsigned short*)wsalloc((size_t)B_ * T_ * 4 * C_ * 2);
  unsigned short* wbuf  = (unsigned short*)wsalloc((size_t)12 * C_ * C_ * 2);
  float* lnfb           = (float*)wsalloc((size_t)B_ * C_ * 4);

  const size_t OFF_AO = (size_t)3 * C_ * C_;
  const size_t OFF_FC = (size_t)4 * C_ * C_;
  const size_t OFF_MO = (size_t)8 * C_ * C_;
  const int MROWS = B_ * T_;

  embed_kernel<<<B_ * T_, 192, 0, stream>>>(idx, wte, wpe, xf);

  for (int l = 0; l < L_; ++l) {
    ln_kernel<false><<<B_ * T_, 256, 0, stream>>>(xf, ln1_g + l * C_, ln1_b + l * C_, a_in, nullptr);
    cvtw4_kernel<<<6912, 256, 0, stream>>>(
        w_qkv + (size_t)l * C_ * 3 * C_, w_ao + (size_t)l * C_ * C_,
        w_fc + (size_t)l * C_ * 4 * C_, w_mo + (size_t)l * 4 * C_ * C_, wbuf);
    // qkv: 256x256, 32 m x 9 n = 288 blocks
    gemm256<3><<<288, 512, 0, stream>>>(a_in, wbuf, b_qkv + l * 3 * C_, qkv3, 3 * C_, C_, 9);
    attn_kernel<<<8 * B_ * H_, 256, 0, stream>>>(qkv3, qkv3 + SZH, qkv3 + 2 * SZH, a_in);
    gemm_bt<1><<<64 * 6, 256, 0, stream>>>(a_in, wbuf + OFF_AO, b_ao + l * C_, xf, nullptr, MROWS, C_, C_, 6);
    ln_kernel<false><<<B_ * T_, 256, 0, stream>>>(xf, ln2_g + l * C_, ln2_b + l * C_, a_in, nullptr);
    // fc: 256x256, 32 m x 12 n = 384 blocks
    gemm256<2><<<384, 512, 0, stream>>>(a_in, wbuf + OFF_FC, b_fc + l * 4 * C_, act2, 4 * C_, C_, 12);
    gemm_bt<1><<<64 * 6, 256, 0, stream>>>(act2, wbuf + OFF_MO, b_mo + l * C_, xf, nullptr, MROWS, C_, 4 * C_, 6);
  }

  ln_kernel<true><<<B_, 256, 0, stream>>>(xf, lnf_g, lnf_b, nullptr, lnfb);
  head_kernel<<<(V_ + 3) / 4, 256, 0, stream>>>(lnfb, wte, (float*)d_out);
}

// Round 11
// 3730.698 us; speedup vs baseline: 1.0662x; 1.0662x over previous
//
#include <hip/hip_runtime.h>

#define B_ 8
#define T_ 1024
#define C_ 768
#define H_ 12
#define L_ 12
#define V_ 50257

typedef __bf16 bf16_t;
typedef __bf16 bf16x8 __attribute__((ext_vector_type(8)));
typedef __bf16 bf16x4 __attribute__((ext_vector_type(4)));
typedef float f32x4 __attribute__((ext_vector_type(4)));

#define AS1 __attribute__((address_space(1)))
#define AS3 __attribute__((address_space(3)))

__device__ __forceinline__ unsigned short f2bf(float f) {
  bf16_t h = (bf16_t)f;
  return __builtin_bit_cast(unsigned short, h);
}

__device__ __forceinline__ unsigned short bfbits(bf16_t h) {
  return __builtin_bit_cast(unsigned short, h);
}

// fast gelu: 0.5x(1+erf(x/sqrt2)), erf via Abramowitz-Stegun 7.1.26 (max err 1.5e-7)
__device__ __forceinline__ float fast_gelu(float v) {
  const float xe = v * 0.70710678118f;
  const float ax = fabsf(xe);
  const float t = 1.0f / fmaf(0.3275911f, ax, 1.0f);
  float poly = fmaf(t, 1.061405429f, -1.453152027f);
  poly = fmaf(t, poly, 1.421413741f);
  poly = fmaf(t, poly, -0.284496736f);
  poly = fmaf(t, poly, 0.254829592f);
  poly *= t;
  float er = 1.0f - poly * __expf(-ax * ax);
  er = (xe < 0.0f) ? -er : er;
  return 0.5f * v * (1.0f + er);
}

// ---- DPP 16-lane reductions ----
template<int CTRL>
__device__ __forceinline__ float dppf(float x) {
  return __builtin_bit_cast(float, __builtin_amdgcn_update_dpp(
      0, __builtin_bit_cast(int, x), CTRL, 0xF, 0xF, true));
}
__device__ __forceinline__ float red16_max(float x) {
  x = fmaxf(x, dppf<0xB1>(x));
  x = fmaxf(x, dppf<0x4E>(x));
  x = fmaxf(x, dppf<0x124>(x));
  x = fmaxf(x, dppf<0x128>(x));
  return x;
}
__device__ __forceinline__ float red16_sum(float x) {
  x += dppf<0xB1>(x);
  x += dppf<0x4E>(x);
  x += dppf<0x124>(x);
  x += dppf<0x128>(x);
  return x;
}

// ---------------- embedding ----------------
__global__ __launch_bounds__(192) void embed_kernel(
    const int* __restrict__ idx, const float* __restrict__ wte,
    const float* __restrict__ wpe, float* __restrict__ xf)
{
  const int bt = blockIdx.x;
  const int t = bt & (T_ - 1);
  const int tok = idx[bt];
  const int c4 = threadIdx.x << 2;
  float4 a = *(const float4*)(wte + (size_t)tok * C_ + c4);
  float4 p = *(const float4*)(wpe + (size_t)t * C_ + c4);
  float4 r; r.x = a.x + p.x; r.y = a.y + p.y; r.z = a.z + p.z; r.w = a.w + p.w;
  *(float4*)(xf + (size_t)bt * C_ + c4) = r;
}

// ---------------- layernorm ----------------
template<bool LAST>
__global__ __launch_bounds__(256) void ln_kernel(
    const float* __restrict__ x, const float* __restrict__ gw,
    const float* __restrict__ bw, unsigned short* __restrict__ obf,
    float* __restrict__ of)
{
  __shared__ float red[8];
  const size_t row = LAST ? ((size_t)blockIdx.x * T_ + (T_ - 1)) : (size_t)blockIdx.x;
  const float* xr = x + row * C_;
  const int t = threadIdx.x;
  float v0 = xr[t], v1 = xr[t + 256], v2 = xr[t + 512];
  float s = v0 + v1 + v2;
  #pragma unroll
  for (int off = 32; off; off >>= 1) s += __shfl_xor(s, off);
  if ((t & 63) == 0) red[t >> 6] = s;
  __syncthreads();
  const float mean = (red[0] + red[1] + red[2] + red[3]) * (1.0f / C_);
  const float d0 = v0 - mean, d1 = v1 - mean, d2 = v2 - mean;
  float ss = d0 * d0 + d1 * d1 + d2 * d2;
  #pragma unroll
  for (int off = 32; off; off >>= 1) ss += __shfl_xor(ss, off);
  if ((t & 63) == 0) red[4 + (t >> 6)] = ss;
  __syncthreads();
  const float var = (red[4] + red[5] + red[6] + red[7]) * (1.0f / C_);
  const float rs = rsqrtf(var + 1e-5f);
  float o0 = d0 * rs * gw[t] + bw[t];
  float o1 = d1 * rs * gw[t + 256] + bw[t + 256];
  float o2 = d2 * rs * gw[t + 512] + bw[t + 512];
  if (LAST) {
    float* orow = of + (size_t)blockIdx.x * C_;
    orow[t] = o0; orow[t + 256] = o1; orow[t + 512] = o2;
  } else {
    unsigned short* orow = obf + row * C_;
    orow[t] = f2bf(o0); orow[t + 256] = f2bf(o1); orow[t + 512] = f2bf(o2);
  }
}

// ---------------- all-layers weight convert (hoisted out of layer loop) ----------------
// blockIdx.x = layer*6912 + piece. Output per layer: qkv | ao | fc | mo (12*C*C elems)
__global__ __launch_bounds__(256) void cvtwall_kernel(
    const float* __restrict__ wq0, const float* __restrict__ wa0,
    const float* __restrict__ wf0, const float* __restrict__ wm0,
    unsigned short* __restrict__ out0)
{
  __shared__ float tile[32][33];
  const int l = blockIdx.x / 6912;
  const int i = blockIdx.x - l * 6912;
  const float* wq = wq0 + (size_t)l * C_ * 3 * C_;
  const float* wa = wa0 + (size_t)l * C_ * C_;
  const float* wf = wf0 + (size_t)l * C_ * 4 * C_;
  const float* wm = wm0 + (size_t)l * 4 * C_ * C_;
  unsigned short* out = out0 + (size_t)l * 12 * C_ * C_;
  const float* W; unsigned short* Wt; int K, N, tix;
  if (i < 1728)      { W = wq; Wt = out;                 K = C_;     N = 3 * C_; tix = i; }
  else if (i < 2304) { W = wa; Wt = out + 3 * C_ * C_;   K = C_;     N = C_;     tix = i - 1728; }
  else if (i < 4608) { W = wf; Wt = out + 4 * C_ * C_;   K = C_;     N = 4 * C_; tix = i - 2304; }
  else               { W = wm; Wt = out + 8 * C_ * C_;   K = 4 * C_; N = C_;     tix = i - 4608; }
  const int ntx = N >> 5;
  const int kb = (tix / ntx) << 5, nb = (tix % ntx) << 5;
  const int t = threadIdx.x;
  {
    const int k = t >> 3, n4 = (t & 7) << 2;
    float4 v = *(const float4*)(W + (size_t)(kb + k) * N + nb + n4);
    tile[k][n4] = v.x; tile[k][n4 + 1] = v.y; tile[k][n4 + 2] = v.z; tile[k][n4 + 3] = v.w;
  }
  __syncthreads();
  {
    const int n = t >> 3, k4 = (t & 7) << 2;
    ushort4 o;
    o.x = f2bf(tile[k4][n]);     o.y = f2bf(tile[k4 + 1][n]);
    o.z = f2bf(tile[k4 + 2][n]); o.w = f2bf(tile[k4 + 3][n]);
    *(ushort4*)(Wt + (size_t)(nb + n) * K + kb + k4) = o;
  }
}

// ---------------- GEMM v4: single-buffered m97 pattern, 4 blocks/CU ----------------
// C[M,N] = A[M,K](bf16) @ Bt[N,K]^T(bf16) + bias
// BM=BN=128, BK=64, 4 waves (2x2), per-wave 64x64 (4x4 16x16x32 frags).
// Single LDS buffer (32KB) -> 4 blocks/CU (16 waves): cross-block TLP fills the
// stage/drain stalls (m97 regime). Involution chunk swizzle keeps reads 2-way-free.
// EPI 1: fp32 += residual. 2: gelu->bf16. 3: qkv split->bf16 [b,h,t,d].
template<int EPI>
__global__ __launch_bounds__(256, 4) void gemm_bt(
    const unsigned short* __restrict__ A, const unsigned short* __restrict__ Bt,
    const float* __restrict__ bias, float* __restrict__ Cf,
    unsigned short* __restrict__ Cb, int M, int N, int K, int nx)
{
  (void)M; (void)nx;
  __shared__ unsigned short As[128 * 64];
  __shared__ unsigned short Bs[128 * 64];
  const int tid = threadIdx.x;
  const int lane = tid & 63;
  const int w = tid >> 6;
  const int wr = w >> 1, wc = w & 1;
  const int l15 = lane & 15, l4 = lane >> 4;
  const int swz = lane & 7;

  // m-slice-per-XCD mapping (r6 proven): xcd owns rows [xcd*1024,(xcd+1)*1024)
  const int bid = blockIdx.x;
  const int xcd = bid & 7;
  const int j = bid >> 3;
  const int mblk = xcd * 8 + (j & 7);
  const int nblk = j >> 3;
  const int m0 = mblk * 128, n0 = nblk * 128;

  f32x4 acc[4][4] = {};

  const int srow = lane >> 3;           // 0..7
  const int schunk = (lane & 7) ^ srow; // pre-swizzled 16B chunk (involution)
  const unsigned short* aSrc = A + (size_t)(m0 + w * 32 + srow) * K + schunk * 8;
  const unsigned short* bSrc = Bt + (size_t)(n0 + w * 32 + srow) * K + schunk * 8;
  const int ldsRowBase = (w * 32) * 64;

  auto stage = [&](int kt) {
    const int k0 = kt << 6;
    #pragma unroll
    for (int jj = 0; jj < 4; ++jj)
      __builtin_amdgcn_global_load_lds(
          (const AS1 unsigned int*)(aSrc + (size_t)jj * 8 * K + k0),
          (AS3 unsigned int*)(&As[ldsRowBase + jj * 8 * 64]), 16, 0, 0);
    #pragma unroll
    for (int jj = 0; jj < 4; ++jj)
      __builtin_amdgcn_global_load_lds(
          (const AS1 unsigned int*)(bSrc + (size_t)jj * 8 * K + k0),
          (AS3 unsigned int*)(&Bs[ldsRowBase + jj * 8 * 64]), 16, 0, 0);
  };

  auto compute = [&]() {
    const unsigned short* aw = &As[(wr * 64) * 64];
    const unsigned short* bw2 = &Bs[(wc * 64) * 64];
    #pragma unroll
    for (int ks = 0; ks < 2; ++ks) {
      bf16x8 af[4], bf[4];
      #pragma unroll
      for (int mf = 0; mf < 4; ++mf)
        af[mf] = *(const bf16x8*)(aw + (mf * 16 + l15) * 64 + (((ks << 2) | l4) ^ swz) * 8);
      #pragma unroll
      for (int nf = 0; nf < 4; ++nf)
        bf[nf] = *(const bf16x8*)(bw2 + (nf * 16 + l15) * 64 + (((ks << 2) | l4) ^ swz) * 8);
      __builtin_amdgcn_s_setprio(1);
      #pragma unroll
      for (int mf = 0; mf < 4; ++mf)
        #pragma unroll
        for (int nf = 0; nf < 4; ++nf)
          acc[mf][nf] = __builtin_amdgcn_mfma_f32_16x16x32_bf16(af[mf], bf[nf], acc[mf][nf], 0, 0, 0);
      __builtin_amdgcn_s_setprio(0);
    }
  };

  const int nk = K >> 6;
  for (int kt = 0; kt < nk; ++kt) {
    stage(kt);
    __syncthreads();   // drains vmcnt(0): staged tile visible
    compute();
    __syncthreads();   // LDS safe to overwrite next iter
  }

  #pragma unroll
  for (int mf = 0; mf < 4; ++mf) {
    #pragma unroll
    for (int nf = 0; nf < 4; ++nf) {
      const int col = n0 + wc * 64 + nf * 16 + l15;
      const float bv = bias[col];
      int hh = 0, dd = 0;
      unsigned short* qkvo = nullptr;
      if constexpr (EPI == 3) {
        const int which = col / C_;
        const int rem = col - which * C_;
        hh = rem >> 6; dd = rem & 63;
        qkvo = Cb + (size_t)which * ((size_t)B_ * H_ * T_ * 64);
      }
      #pragma unroll
      for (int i = 0; i < 4; ++i) {
        const int row = m0 + wr * 64 + mf * 16 + l4 * 4 + i;
        float v = acc[mf][nf][i] + bv;
        if constexpr (EPI == 1) {
          Cf[(size_t)row * N + col] += v;
        } else if constexpr (EPI == 2) {
          Cb[(size_t)row * N + col] = f2bf(fast_gelu(v));
        } else {
          const int bb = row >> 10, tt = row & (T_ - 1);
          qkvo[(((size_t)bb * H_ + hh) * T_ + tt) * 64 + dd] = f2bf(v);
        }
      }
    }
  }
}

// ---------------- flash attention v5 (r9: dual-band balance + defer-max) ----------------
__global__ __launch_bounds__(256) void attn_kernel(
    const unsigned short* __restrict__ Qb, const unsigned short* __restrict__ Kb,
    const unsigned short* __restrict__ Vb, unsigned short* __restrict__ y)
{
  const int pb = blockIdx.x / 96;
  const int bh = blockIdx.x % 96;
  const int h = bh % H_;
  const int b = bh / H_;
  const int tid = threadIdx.x, lane = tid & 63, w = tid >> 6;
  const int l15 = lane & 15, l4 = lane >> 4;

  const int qband0 = pb * 64 + w * 16;
  const int qband1 = (15 - pb) * 64 + w * 16;
  const int NT = (17 - pb) >> 1;

  __shared__ unsigned short Ks[128 * 64];
  __shared__ unsigned short Vt[64 * 136];
  __shared__ unsigned short Pb[4][32 * 74];

  bf16x8 qf[2][2];
  {
    const unsigned short* q0p = Qb + ((size_t)bh * T_ + qband0) * 64;
    const unsigned short* q1p = Qb + ((size_t)bh * T_ + qband1) * 64;
    #pragma unroll
    for (int ks = 0; ks < 2; ++ks) {
      qf[0][ks] = *(const bf16x8*)(q0p + l15 * 64 + ks * 32 + l4 * 8);
      qf[1][ks] = *(const bf16x8*)(q1p + l15 * 64 + ks * 32 + l4 * 8);
    }
  }

  f32x4 o[2][4] = {};
  float mrow[2][4], lrow[2][4];
  #pragma unroll
  for (int mf = 0; mf < 2; ++mf)
    #pragma unroll
    for (int i = 0; i < 4; ++i) { mrow[mf][i] = -1e30f; lrow[mf][i] = 0.0f; }

  const unsigned short* kb0 = Kb + (size_t)bh * T_ * 64;
  const unsigned short* vb0 = Vb + (size_t)bh * T_ * 64;
  const int ck = w;
  const int skey = lane;
  const int sw = (skey & 7);

  bf16x8 kr0, kr1, kr2, kr3, vr0, vr1, vr2, vr3;
  {
    const unsigned short* kp = kb0 + (size_t)skey * 64;
    const unsigned short* vp = vb0 + (size_t)skey * 64;
    kr0 = *(const bf16x8*)(kp + ck * 8);
    kr1 = *(const bf16x8*)(kp + (ck + 4) * 8);
    kr2 = *(const bf16x8*)(kp + 64 * 64 + ck * 8);
    kr3 = *(const bf16x8*)(kp + 64 * 64 + (ck + 4) * 8);
    vr0 = *(const bf16x8*)(vp + ck * 8);
    vr1 = *(const bf16x8*)(vp + (ck + 4) * 8);
    vr2 = *(const bf16x8*)(vp + 64 * 64 + ck * 8);
    vr3 = *(const bf16x8*)(vp + 64 * 64 + (ck + 4) * 8);
  }

  for (int kt = 0; kt < NT; ++kt) {
    const int k0 = kt << 7;
    __syncthreads();
    *(bf16x8*)(Ks + skey * 64 + ((ck ^ sw) * 8)) = kr0;
    *(bf16x8*)(Ks + skey * 64 + (((ck + 4) ^ sw) * 8)) = kr1;
    *(bf16x8*)(Ks + (skey + 64) * 64 + ((ck ^ sw) * 8)) = kr2;
    *(bf16x8*)(Ks + (skey + 64) * 64 + (((ck + 4) ^ sw) * 8)) = kr3;
    #pragma unroll
    for (int jj = 0; jj < 8; ++jj) {
      Vt[(ck * 8 + jj) * 136 + skey]            = bfbits(vr0[jj]);
      Vt[((ck + 4) * 8 + jj) * 136 + skey]      = bfbits(vr1[jj]);
      Vt[(ck * 8 + jj) * 136 + skey + 64]       = bfbits(vr2[jj]);
      Vt[((ck + 4) * 8 + jj) * 136 + skey + 64] = bfbits(vr3[jj]);
    }
    __syncthreads();
    if (kt + 1 < NT) {
      const int kn = (kt + 1) << 7;
      const unsigned short* kp = kb0 + (size_t)(kn + skey) * 64;
      const unsigned short* vp = vb0 + (size_t)(kn + skey) * 64;
      kr0 = *(const bf16x8*)(kp + ck * 8);
      kr1 = *(const bf16x8*)(kp + (ck + 4) * 8);
      kr2 = *(const bf16x8*)(kp + 64 * 64 + ck * 8);
      kr3 = *(const bf16x8*)(kp + 64 * 64 + (ck + 4) * 8);
      vr0 = *(const bf16x8*)(vp + ck * 8);
      vr1 = *(const bf16x8*)(vp + (ck + 4) * 8);
      vr2 = *(const bf16x8*)(vp + 64 * 64 + ck * 8);
      vr3 = *(const bf16x8*)(vp + 64 * 64 + (ck + 4) * 8);
    }

    #pragma unroll
    for (int h2 = 0; h2 < 2; ++h2) {
      const int kh0 = k0 + h2 * 64;
      const bool act0 = (kh0 <= qband0 + 15);
      const bool act1 = (kh0 <= qband1 + 15);
      if (!act0 && !act1) continue;

      f32x4 s[2][4] = {};
      __builtin_amdgcn_s_setprio(1);
      #pragma unroll
      for (int ks = 0; ks < 2; ++ks) {
        #pragma unroll
        for (int nfk = 0; nfk < 4; ++nfk) {
          const int key = h2 * 64 + nfk * 16 + l15;
          bf16x8 kf = *(const bf16x8*)(Ks + key * 64 + ((((ks << 2) | l4) ^ (l15 & 7)) * 8));
          if (act0) s[0][nfk] = __builtin_amdgcn_mfma_f32_16x16x32_bf16(qf[0][ks], kf, s[0][nfk], 0, 0, 0);
          if (act1) s[1][nfk] = __builtin_amdgcn_mfma_f32_16x16x32_bf16(qf[1][ks], kf, s[1][nfk], 0, 0, 0);
        }
      }
      __builtin_amdgcn_s_setprio(0);

      #pragma unroll
      for (int mf = 0; mf < 2; ++mf) {
        const bool act = mf ? act1 : act0;
        if (!act) continue;
        const int qb0 = mf ? qband1 : qband0;
        const int qrow = qb0 + l4 * 4;
        const bool fullt = (kh0 + 63) <= qb0;
        float pvv[4][4], tm[4];
        #pragma unroll
        for (int i = 0; i < 4; ++i) {
          const int q = qrow + i;
          float m_ = -1e30f;
          #pragma unroll
          for (int nfk = 0; nfk < 4; ++nfk) {
            float x = s[mf][nfk][i] * 0.125f;
            x = fullt ? x : ((kh0 + nfk * 16 + l15 <= q) ? x : -1e30f);
            pvv[nfk][i] = x;
            m_ = fmaxf(m_, x);
          }
          tm[i] = red16_max(m_);
        }
        bool need = false;
        #pragma unroll
        for (int i = 0; i < 4; ++i) need |= (tm[i] > mrow[mf][i] + 8.0f);
        if (__any(need)) {
          #pragma unroll
          for (int i = 0; i < 4; ++i) {
            const float mnew = fmaxf(mrow[mf][i], tm[i]);
            const float alpha = __expf(mrow[mf][i] - mnew);
            mrow[mf][i] = mnew;
            lrow[mf][i] *= alpha;
            #pragma unroll
            for (int nf = 0; nf < 4; ++nf) o[mf][nf][i] *= alpha;
          }
        }
        #pragma unroll
        for (int i = 0; i < 4; ++i) {
          float rsum = 0.0f;
          #pragma unroll
          for (int nfk = 0; nfk < 4; ++nfk) {
            const float p = __expf(pvv[nfk][i] - mrow[mf][i]);
            pvv[nfk][i] = p; rsum += p;
          }
          rsum = red16_sum(rsum);
          lrow[mf][i] += rsum;
        }
        #pragma unroll
        for (int nfk = 0; nfk < 4; ++nfk)
          #pragma unroll
          for (int i = 0; i < 4; ++i)
            Pb[w][(mf * 16 + l4 * 4 + i) * 74 + nfk * 16 + l15] = f2bf(pvv[nfk][i]);
      }

      bf16x8 pa[2][2];
      #pragma unroll
      for (int mf = 0; mf < 2; ++mf)
        if (mf ? act1 : act0)
          #pragma unroll
          for (int k2 = 0; k2 < 2; ++k2)
            pa[mf][k2] = *(const bf16x8*)(Pb[w] + (mf * 16 + l15) * 74 + k2 * 32 + l4 * 8);
      __builtin_amdgcn_s_setprio(1);
      #pragma unroll
      for (int nf = 0; nf < 4; ++nf) {
        const int d = nf * 16 + l15;
        #pragma unroll
        for (int k2 = 0; k2 < 2; ++k2) {
          bf16x8 vf = *(const bf16x8*)(Vt + d * 136 + h2 * 64 + k2 * 32 + l4 * 8);
          if (act0) o[0][nf] = __builtin_amdgcn_mfma_f32_16x16x32_bf16(pa[0][k2], vf, o[0][nf], 0, 0, 0);
          if (act1) o[1][nf] = __builtin_amdgcn_mfma_f32_16x16x32_bf16(pa[1][k2], vf, o[1][nf], 0, 0, 0);
        }
      }
      __builtin_amdgcn_s_setprio(0);
    }
  }

  #pragma unroll
  for (int mf = 0; mf < 2; ++mf) {
    const int qb0 = mf ? qband1 : qband0;
    #pragma unroll
    for (int i = 0; i < 4; ++i) {
      const float inv = 1.0f / lrow[mf][i];
      const int q = qb0 + l4 * 4 + i;
      unsigned short* yr = y + (size_t)(b * T_ + q) * C_ + h * 64;
      #pragma unroll
      for (int nf = 0; nf < 4; ++nf)
        yr[nf * 16 + l15] = f2bf(o[mf][nf][i] * inv);
    }
  }
}

// ---------------- head ----------------
__global__ __launch_bounds__(256) void head_kernel(
    const float* __restrict__ lnf, const float* __restrict__ wte,
    float* __restrict__ out)
{
  __shared__ float xs[B_ * C_];
  for (int i = threadIdx.x; i < B_ * C_; i += 256) xs[i] = lnf[i];
  __syncthreads();
  const int w = threadIdx.x >> 6, lane = threadIdx.x & 63;
  const int v = blockIdx.x * 4 + w;
  if (v >= V_) return;
  const float* wv = wte + (size_t)v * C_ + lane * 12;
  float4 w0 = *(const float4*)(wv);
  float4 w1 = *(const float4*)(wv + 4);
  float4 w2 = *(const float4*)(wv + 8);
  float acc[B_];
  #pragma unroll
  for (int bb = 0; bb < B_; ++bb) {
    const float* xr = xs + bb * C_ + lane * 12;
    float4 x0 = *(const float4*)(xr);
    float4 x1 = *(const float4*)(xr + 4);
    float4 x2 = *(const float4*)(xr + 8);
    acc[bb] = w0.x * x0.x + w0.y * x0.y + w0.z * x0.z + w0.w * x0.w
            + w1.x * x1.x + w1.y * x1.y + w1.z * x1.z + w1.w * x1.w
            + w2.x * x2.x + w2.y * x2.y + w2.z * x2.z + w2.w * x2.w;
  }
  #pragma unroll
  for (int off = 32; off; off >>= 1) {
    #pragma unroll
    for (int bb = 0; bb < B_; ++bb)
      acc[bb] += __shfl_xor(acc[bb], off);
  }
  if (lane == 0) {
    #pragma unroll
    for (int bb = 0; bb < B_; ++bb)
      out[(size_t)bb * V_ + v] = acc[bb];
  }
}

// ---------------- launcher ----------------
extern "C" void kernel_launch(void* const* d_in, const int* in_sizes, int n_in,
                              void* d_out, int out_size, void* d_ws, size_t ws_size,
                              hipStream_t stream)
{
  (void)in_sizes; (void)n_in; (void)out_size; (void)ws_size;
  const int*   idx   = (const int*)d_in[0];
  const float* wte   = (const float*)d_in[1];
  const float* wpe   = (const float*)d_in[2];
  const float* ln1_g = (const float*)d_in[3];
  const float* ln1_b = (const float*)d_in[4];
  const float* w_qkv = (const float*)d_in[5];
  const float* b_qkv = (const float*)d_in[6];
  const float* w_ao  = (const float*)d_in[7];
  const float* b_ao  = (const float*)d_in[8];
  const float* ln2_g = (const float*)d_in[9];
  const float* ln2_b = (const float*)d_in[10];
  const float* w_fc  = (const float*)d_in[11];
  const float* b_fc  = (const float*)d_in[12];
  const float* w_mo  = (const float*)d_in[13];
  const float* b_mo  = (const float*)d_in[14];
  const float* lnf_g = (const float*)d_in[15];
  const float* lnf_b = (const float*)d_in[16];

  char* ws = (char*)d_ws;
  size_t off = 0;
  auto wsalloc = [&](size_t bytes) -> void* {
    void* p = ws + off;
    off += (bytes + 255) & ~(size_t)255;
    return p;
  };
  const size_t SZH = (size_t)B_ * H_ * T_ * 64;
  float* xf             = (float*)wsalloc((size_t)B_ * T_ * C_ * 4);
  unsigned short* qkv3  = (unsigned short*)wsalloc(3 * SZH * 2);
  unsigned short* a_in  = (unsigned short*)wsalloc((size_t)B_ * T_ * C_ * 2);
  unsigned short* act2  = (unsigned short*)wsalloc((size_t)B_ * T_ * 4 * C_ * 2);
  unsigned short* wbuf  = (unsigned short*)wsalloc((size_t)L_ * 12 * C_ * C_ * 2);
  float* lnfb           = (float*)wsalloc((size_t)B_ * C_ * 4);

  const size_t WSTRIDE = (size_t)12 * C_ * C_;
  const size_t OFF_AO = (size_t)3 * C_ * C_;
  const size_t OFF_FC = (size_t)4 * C_ * C_;
  const size_t OFF_MO = (size_t)8 * C_ * C_;
  const int MROWS = B_ * T_;

  embed_kernel<<<B_ * T_, 192, 0, stream>>>(idx, wte, wpe, xf);
  cvtwall_kernel<<<L_ * 6912, 256, 0, stream>>>(w_qkv, w_ao, w_fc, w_mo, wbuf);

  for (int l = 0; l < L_; ++l) {
    unsigned short* wb = wbuf + (size_t)l * WSTRIDE;
    ln_kernel<false><<<B_ * T_, 256, 0, stream>>>(xf, ln1_g + l * C_, ln1_b + l * C_, a_in, nullptr);
    gemm_bt<3><<<64 * 18, 256, 0, stream>>>(a_in, wb, b_qkv + l * 3 * C_, nullptr, qkv3, MROWS, 3 * C_, C_, 18);
    attn_kernel<<<8 * B_ * H_, 256, 0, stream>>>(qkv3, qkv3 + SZH, qkv3 + 2 * SZH, a_in);
    gemm_bt<1><<<64 * 6, 256, 0, stream>>>(a_in, wb + OFF_AO, b_ao + l * C_, xf, nullptr, MROWS, C_, C_, 6);
    ln_kernel<false><<<B_ * T_, 256, 0, stream>>>(xf, ln2_g + l * C_, ln2_b + l * C_, a_in, nullptr);
    gemm_bt<2><<<64 * 24, 256, 0, stream>>>(a_in, wb + OFF_FC, b_fc + l * 4 * C_, nullptr, act2, MROWS, 4 * C_, C_, 24);
    gemm_bt<1><<<64 * 6, 256, 0, stream>>>(act2, wb + OFF_MO, b_mo + l * C_, xf, nullptr, MROWS, C_, 4 * C_, 6);
  }

  ln_kernel<true><<<B_, 256, 0, stream>>>(xf, lnf_g, lnf_b, nullptr, lnfb);
  head_kernel<<<(V_ + 3) / 4, 256, 0, stream>>>(lnfb, wte, (float*)d_out);
}

// Round 12
// 3527.200 us; speedup vs baseline: 1.1277x; 1.0577x over previous
//
#include <hip/hip_runtime.h>

#define B_ 8
#define T_ 1024
#define C_ 768
#define H_ 12
#define L_ 12
#define V_ 50257

typedef __bf16 bf16_t;
typedef __bf16 bf16x8 __attribute__((ext_vector_type(8)));
typedef __bf16 bf16x4 __attribute__((ext_vector_type(4)));
typedef float f32x4 __attribute__((ext_vector_type(4)));

#define AS1 __attribute__((address_space(1)))
#define AS3 __attribute__((address_space(3)))

__device__ __forceinline__ unsigned short f2bf(float f) {
  bf16_t h = (bf16_t)f;
  return __builtin_bit_cast(unsigned short, h);
}

__device__ __forceinline__ unsigned short bfbits(bf16_t h) {
  return __builtin_bit_cast(unsigned short, h);
}

// fast gelu: 0.5x(1+erf(x/sqrt2)), erf via Abramowitz-Stegun 7.1.26 (max err 1.5e-7)
__device__ __forceinline__ float fast_gelu(float v) {
  const float xe = v * 0.70710678118f;
  const float ax = fabsf(xe);
  const float t = 1.0f / fmaf(0.3275911f, ax, 1.0f);
  float poly = fmaf(t, 1.061405429f, -1.453152027f);
  poly = fmaf(t, poly, 1.421413741f);
  poly = fmaf(t, poly, -0.284496736f);
  poly = fmaf(t, poly, 0.254829592f);
  poly *= t;
  float er = 1.0f - poly * __expf(-ax * ax);
  er = (xe < 0.0f) ? -er : er;
  return 0.5f * v * (1.0f + er);
}

// ---------------- embedding ----------------
__global__ __launch_bounds__(192) void embed_kernel(
    const int* __restrict__ idx, const float* __restrict__ wte,
    const float* __restrict__ wpe, float* __restrict__ xf)
{
  const int bt = blockIdx.x;
  const int t = bt & (T_ - 1);
  const int tok = idx[bt];
  const int c4 = threadIdx.x << 2;
  float4 a = *(const float4*)(wte + (size_t)tok * C_ + c4);
  float4 p = *(const float4*)(wpe + (size_t)t * C_ + c4);
  float4 r; r.x = a.x + p.x; r.y = a.y + p.y; r.z = a.z + p.z; r.w = a.w + p.w;
  *(float4*)(xf + (size_t)bt * C_ + c4) = r;
}

// ---------------- layernorm ----------------
template<bool LAST>
__global__ __launch_bounds__(256) void ln_kernel(
    const float* __restrict__ x, const float* __restrict__ gw,
    const float* __restrict__ bw, unsigned short* __restrict__ obf,
    float* __restrict__ of)
{
  __shared__ float red[8];
  const size_t row = LAST ? ((size_t)blockIdx.x * T_ + (T_ - 1)) : (size_t)blockIdx.x;
  const float* xr = x + row * C_;
  const int t = threadIdx.x;
  float v0 = xr[t], v1 = xr[t + 256], v2 = xr[t + 512];
  float s = v0 + v1 + v2;
  #pragma unroll
  for (int off = 32; off; off >>= 1) s += __shfl_xor(s, off);
  if ((t & 63) == 0) red[t >> 6] = s;
  __syncthreads();
  const float mean = (red[0] + red[1] + red[2] + red[3]) * (1.0f / C_);
  const float d0 = v0 - mean, d1 = v1 - mean, d2 = v2 - mean;
  float ss = d0 * d0 + d1 * d1 + d2 * d2;
  #pragma unroll
  for (int off = 32; off; off >>= 1) ss += __shfl_xor(ss, off);
  if ((t & 63) == 0) red[4 + (t >> 6)] = ss;
  __syncthreads();
  const float var = (red[4] + red[5] + red[6] + red[7]) * (1.0f / C_);
  const float rs = rsqrtf(var + 1e-5f);
  float o0 = d0 * rs * gw[t] + bw[t];
  float o1 = d1 * rs * gw[t + 256] + bw[t + 256];
  float o2 = d2 * rs * gw[t + 512] + bw[t + 512];
  if (LAST) {
    float* orow = of + (size_t)blockIdx.x * C_;
    orow[t] = o0; orow[t + 256] = o1; orow[t + 512] = o2;
  } else {
    unsigned short* orow = obf + row * C_;
    orow[t] = f2bf(o0); orow[t + 256] = f2bf(o1); orow[t + 512] = f2bf(o2);
  }
}

// ---------------- fused weight convert (per-layer, r9 proven) ----------------
__global__ __launch_bounds__(256) void cvtw4_kernel(
    const float* __restrict__ wq, const float* __restrict__ wa,
    const float* __restrict__ wf, const float* __restrict__ wm,
    unsigned short* __restrict__ out)
{
  __shared__ float tile[32][33];
  const int i = blockIdx.x;
  const float* W; unsigned short* Wt; int K, N, tix;
  if (i < 1728)      { W = wq; Wt = out;                 K = C_;     N = 3 * C_; tix = i; }
  else if (i < 2304) { W = wa; Wt = out + 3 * C_ * C_;   K = C_;     N = C_;     tix = i - 1728; }
  else if (i < 4608) { W = wf; Wt = out + 4 * C_ * C_;   K = C_;     N = 4 * C_; tix = i - 2304; }
  else               { W = wm; Wt = out + 8 * C_ * C_;   K = 4 * C_; N = C_;     tix = i - 4608; }
  const int ntx = N >> 5;
  const int kb = (tix / ntx) << 5, nb = (tix % ntx) << 5;
  const int t = threadIdx.x;
  {
    const int k = t >> 3, n4 = (t & 7) << 2;
    float4 v = *(const float4*)(W + (size_t)(kb + k) * N + nb + n4);
    tile[k][n4] = v.x; tile[k][n4 + 1] = v.y; tile[k][n4 + 2] = v.z; tile[k][n4 + 3] = v.w;
  }
  __syncthreads();
  {
    const int n = t >> 3, k4 = (t & 7) << 2;
    ushort4 o;
    o.x = f2bf(tile[k4][n]);     o.y = f2bf(tile[k4 + 1][n]);
    o.z = f2bf(tile[k4 + 2][n]); o.w = f2bf(tile[k4 + 3][n]);
    *(ushort4*)(Wt + (size_t)(nb + n) * K + kb + k4) = o;
  }
}

// ---------------- GEMM: counted-vmcnt double-buffered pipeline (r6/r9 proven) ----------------
// BM=BN=128, BK=64, 4 waves (2x2), per-wave 64x64 (4x4 16x16x32 frags), 2 blocks/CU.
template<int EPI>
__global__ __launch_bounds__(256, 2) void gemm_bt(
    const unsigned short* __restrict__ A, const unsigned short* __restrict__ Bt,
    const float* __restrict__ bias, float* __restrict__ Cf,
    unsigned short* __restrict__ Cb, int M, int N, int K, int nx)
{
  (void)M; (void)nx;
  __shared__ unsigned short As[2][128 * 64];
  __shared__ unsigned short Bs[2][128 * 64];
  const int tid = threadIdx.x;
  const int lane = tid & 63;
  const int w = tid >> 6;
  const int wr = w >> 1, wc = w & 1;
  const int l15 = lane & 15, l4 = lane >> 4;
  const int swz = lane & 7;

  // m-slice-per-XCD mapping: xcd owns 8 m-blocks, m-sub fast within XCD
  const int bid = blockIdx.x;
  const int xcd = bid & 7;
  const int j = bid >> 3;
  const int mblk = xcd * 8 + (j & 7);
  const int nblk = j >> 3;
  const int m0 = mblk * 128, n0 = nblk * 128;

  f32x4 acc[4][4] = {};

  const int srow = lane >> 3;           // 0..7
  const int schunk = (lane & 7) ^ srow; // pre-swizzled 16B chunk (involution)
  const unsigned short* aSrc = A + (size_t)(m0 + w * 32 + srow) * K + schunk * 8;
  const unsigned short* bSrc = Bt + (size_t)(n0 + w * 32 + srow) * K + schunk * 8;
  const int ldsRowBase = (w * 32) * 64;

  auto stage = [&](int kt, int p) {
    const int k0 = kt << 6;
    #pragma unroll
    for (int jj = 0; jj < 4; ++jj)
      __builtin_amdgcn_global_load_lds(
          (const AS1 unsigned int*)(aSrc + (size_t)jj * 8 * K + k0),
          (AS3 unsigned int*)(&As[p][ldsRowBase + jj * 8 * 64]), 16, 0, 0);
    #pragma unroll
    for (int jj = 0; jj < 4; ++jj)
      __builtin_amdgcn_global_load_lds(
          (const AS1 unsigned int*)(bSrc + (size_t)jj * 8 * K + k0),
          (AS3 unsigned int*)(&Bs[p][ldsRowBase + jj * 8 * 64]), 16, 0, 0);
  };

  auto compute = [&](int p) {
    const unsigned short* aw = &As[p][(wr * 64) * 64];
    const unsigned short* bw2 = &Bs[p][(wc * 64) * 64];
    #pragma unroll
    for (int ks = 0; ks < 2; ++ks) {
      bf16x8 af[4], bf[4];
      #pragma unroll
      for (int mf = 0; mf < 4; ++mf)
        af[mf] = *(const bf16x8*)(aw + (mf * 16 + l15) * 64 + (((ks << 2) | l4) ^ swz) * 8);
      #pragma unroll
      for (int nf = 0; nf < 4; ++nf)
        bf[nf] = *(const bf16x8*)(bw2 + (nf * 16 + l15) * 64 + (((ks << 2) | l4) ^ swz) * 8);
      __builtin_amdgcn_s_setprio(1);
      #pragma unroll
      for (int mf = 0; mf < 4; ++mf)
        #pragma unroll
        for (int nf = 0; nf < 4; ++nf)
          acc[mf][nf] = __builtin_amdgcn_mfma_f32_16x16x32_bf16(af[mf], bf[nf], acc[mf][nf], 0, 0, 0);
      __builtin_amdgcn_s_setprio(0);
    }
  };

  const int nk = K >> 6;
  stage(0, 0);
  for (int kt = 0; kt < nk - 1; ++kt) {
    const int p = kt & 1;
    stage(kt + 1, p ^ 1);
    asm volatile("s_waitcnt vmcnt(8)" ::: "memory");
    __builtin_amdgcn_s_barrier();
    compute(p);
    __builtin_amdgcn_s_barrier();
  }
  asm volatile("s_waitcnt vmcnt(0)" ::: "memory");
  __builtin_amdgcn_s_barrier();
  compute((nk - 1) & 1);

  #pragma unroll
  for (int mf = 0; mf < 4; ++mf) {
    #pragma unroll
    for (int nf = 0; nf < 4; ++nf) {
      const int col = n0 + wc * 64 + nf * 16 + l15;
      const float bv = bias[col];
      int hh = 0, dd = 0;
      unsigned short* qkvo = nullptr;
      if constexpr (EPI == 3) {
        const int which = col / C_;
        const int rem = col - which * C_;
        hh = rem >> 6; dd = rem & 63;
        qkvo = Cb + (size_t)which * ((size_t)B_ * H_ * T_ * 64);
      }
      #pragma unroll
      for (int i = 0; i < 4; ++i) {
        const int row = m0 + wr * 64 + mf * 16 + l4 * 4 + i;
        float v = acc[mf][nf][i] + bv;
        if constexpr (EPI == 1) {
          Cf[(size_t)row * N + col] += v;
        } else if constexpr (EPI == 2) {
          Cb[(size_t)row * N + col] = f2bf(fast_gelu(v));
        } else {
          const int bb = row >> 10, tt = row & (T_ - 1);
          qkvo[(((size_t)bb * H_ + hh) * T_ + tt) * 64 + dd] = f2bf(v);
        }
      }
    }
  }
}

// ---------------- flash attention v6: dual-band + no-max streaming softmax ----------------
// Scores are q.k/8 with LN'd activations (|s| << 80): softmax computed WITHOUT
// max-subtraction (mathematically identical, exp cannot overflow here).
// Row-sum via ones-column MFMA (replaces cross-lane DPP reductions entirely).
// Q pre-scaled by 1/8 at load (exact in bf16).
__global__ __launch_bounds__(256) void attn_kernel(
    const unsigned short* __restrict__ Qb, const unsigned short* __restrict__ Kb,
    const unsigned short* __restrict__ Vb, unsigned short* __restrict__ y)
{
  const int pb = blockIdx.x / 96;
  const int bh = blockIdx.x % 96;
  const int h = bh % H_;
  const int b = bh / H_;
  const int tid = threadIdx.x, lane = tid & 63, w = tid >> 6;
  const int l15 = lane & 15, l4 = lane >> 4;

  const int qband0 = pb * 64 + w * 16;          // low chunk band (16 rows)
  const int qband1 = (15 - pb) * 64 + w * 16;   // high chunk band (16 rows)
  const int NT = (17 - pb) >> 1;

  __shared__ unsigned short Ks[128 * 64];
  __shared__ unsigned short Vt[64 * 136];
  __shared__ unsigned short Pb[4][32 * 74];

  bf16x8 qf[2][2];
  {
    const unsigned short* q0p = Qb + ((size_t)bh * T_ + qband0) * 64;
    const unsigned short* q1p = Qb + ((size_t)bh * T_ + qband1) * 64;
    #pragma unroll
    for (int ks = 0; ks < 2; ++ks) {
      qf[0][ks] = *(const bf16x8*)(q0p + l15 * 64 + ks * 32 + l4 * 8);
      qf[1][ks] = *(const bf16x8*)(q1p + l15 * 64 + ks * 32 + l4 * 8);
    }
    // fold 1/sqrt(D)=1/8 into Q (exact: power-of-two exponent shift)
    #pragma unroll
    for (int mf = 0; mf < 2; ++mf)
      #pragma unroll
      for (int ks = 0; ks < 2; ++ks)
        #pragma unroll
        for (int jj = 0; jj < 8; ++jj)
          qf[mf][ks][jj] = (bf16_t)((float)qf[mf][ks][jj] * 0.125f);
  }

  bf16x8 ones;
  #pragma unroll
  for (int jj = 0; jj < 8; ++jj) ones[jj] = (bf16_t)1.0f;

  f32x4 o[2][4] = {};
  f32x4 rs[2] = {};   // per-row softmax denominators (accumulated via ones-MFMA)

  const unsigned short* kb0 = Kb + (size_t)bh * T_ * 64;
  const unsigned short* vb0 = Vb + (size_t)bh * T_ * 64;
  const int ck = w;
  const int skey = lane;
  const int sw = (skey & 7);

  bf16x8 kr0, kr1, kr2, kr3, vr0, vr1, vr2, vr3;
  {
    const unsigned short* kp = kb0 + (size_t)skey * 64;
    const unsigned short* vp = vb0 + (size_t)skey * 64;
    kr0 = *(const bf16x8*)(kp + ck * 8);
    kr1 = *(const bf16x8*)(kp + (ck + 4) * 8);
    kr2 = *(const bf16x8*)(kp + 64 * 64 + ck * 8);
    kr3 = *(const bf16x8*)(kp + 64 * 64 + (ck + 4) * 8);
    vr0 = *(const bf16x8*)(vp + ck * 8);
    vr1 = *(const bf16x8*)(vp + (ck + 4) * 8);
    vr2 = *(const bf16x8*)(vp + 64 * 64 + ck * 8);
    vr3 = *(const bf16x8*)(vp + 64 * 64 + (ck + 4) * 8);
  }

  for (int kt = 0; kt < NT; ++kt) {
    const int k0 = kt << 7;
    __syncthreads();
    *(bf16x8*)(Ks + skey * 64 + ((ck ^ sw) * 8)) = kr0;
    *(bf16x8*)(Ks + skey * 64 + (((ck + 4) ^ sw) * 8)) = kr1;
    *(bf16x8*)(Ks + (skey + 64) * 64 + ((ck ^ sw) * 8)) = kr2;
    *(bf16x8*)(Ks + (skey + 64) * 64 + (((ck + 4) ^ sw) * 8)) = kr3;
    #pragma unroll
    for (int jj = 0; jj < 8; ++jj) {
      Vt[(ck * 8 + jj) * 136 + skey]            = bfbits(vr0[jj]);
      Vt[((ck + 4) * 8 + jj) * 136 + skey]      = bfbits(vr1[jj]);
      Vt[(ck * 8 + jj) * 136 + skey + 64]       = bfbits(vr2[jj]);
      Vt[((ck + 4) * 8 + jj) * 136 + skey + 64] = bfbits(vr3[jj]);
    }
    __syncthreads();
    if (kt + 1 < NT) {
      const int kn = (kt + 1) << 7;
      const unsigned short* kp = kb0 + (size_t)(kn + skey) * 64;
      const unsigned short* vp = vb0 + (size_t)(kn + skey) * 64;
      kr0 = *(const bf16x8*)(kp + ck * 8);
      kr1 = *(const bf16x8*)(kp + (ck + 4) * 8);
      kr2 = *(const bf16x8*)(kp + 64 * 64 + ck * 8);
      kr3 = *(const bf16x8*)(kp + 64 * 64 + (ck + 4) * 8);
      vr0 = *(const bf16x8*)(vp + ck * 8);
      vr1 = *(const bf16x8*)(vp + (ck + 4) * 8);
      vr2 = *(const bf16x8*)(vp + 64 * 64 + ck * 8);
      vr3 = *(const bf16x8*)(vp + 64 * 64 + (ck + 4) * 8);
    }

    #pragma unroll
    for (int h2 = 0; h2 < 2; ++h2) {
      const int kh0 = k0 + h2 * 64;
      const bool act0 = (kh0 <= qband0 + 15);
      const bool act1 = (kh0 <= qband1 + 15);
      if (!act0 && !act1) continue;

      f32x4 s[2][4] = {};
      __builtin_amdgcn_s_setprio(1);
      #pragma unroll
      for (int ks = 0; ks < 2; ++ks) {
        #pragma unroll
        for (int nfk = 0; nfk < 4; ++nfk) {
          const int key = h2 * 64 + nfk * 16 + l15;
          bf16x8 kf = *(const bf16x8*)(Ks + key * 64 + ((((ks << 2) | l4) ^ (l15 & 7)) * 8));
          if (act0) s[0][nfk] = __builtin_amdgcn_mfma_f32_16x16x32_bf16(qf[0][ks], kf, s[0][nfk], 0, 0, 0);
          if (act1) s[1][nfk] = __builtin_amdgcn_mfma_f32_16x16x32_bf16(qf[1][ks], kf, s[1][nfk], 0, 0, 0);
        }
      }
      __builtin_amdgcn_s_setprio(0);

      // no-max streaming softmax: p = exp(s) (masked -> 0); no reductions here
      #pragma unroll
      for (int mf = 0; mf < 2; ++mf) {
        const bool act = mf ? act1 : act0;
        if (!act) continue;
        const int qb0 = mf ? qband1 : qband0;
        const int qrow = qb0 + l4 * 4;
        const bool fullt = (kh0 + 63) <= qb0;
        float pvv[4][4];
        #pragma unroll
        for (int i = 0; i < 4; ++i) {
          const int q = qrow + i;
          #pragma unroll
          for (int nfk = 0; nfk < 4; ++nfk) {
            const bool on = fullt || (kh0 + nfk * 16 + l15 <= q);
            pvv[nfk][i] = on ? __expf(s[mf][nfk][i]) : 0.0f;
          }
        }
        #pragma unroll
        for (int nfk = 0; nfk < 4; ++nfk)
          #pragma unroll
          for (int i = 0; i < 4; ++i)
            Pb[w][(mf * 16 + l4 * 4 + i) * 74 + nfk * 16 + l15] = f2bf(pvv[nfk][i]);
      }

      bf16x8 pa[2][2];
      #pragma unroll
      for (int mf = 0; mf < 2; ++mf)
        if (mf ? act1 : act0)
          #pragma unroll
          for (int k2 = 0; k2 < 2; ++k2)
            pa[mf][k2] = *(const bf16x8*)(Pb[w] + (mf * 16 + l15) * 74 + k2 * 32 + l4 * 8);
      __builtin_amdgcn_s_setprio(1);
      #pragma unroll
      for (int nf = 0; nf < 4; ++nf) {
        const int d = nf * 16 + l15;
        #pragma unroll
        for (int k2 = 0; k2 < 2; ++k2) {
          bf16x8 vf = *(const bf16x8*)(Vt + d * 136 + h2 * 64 + k2 * 32 + l4 * 8);
          if (act0) o[0][nf] = __builtin_amdgcn_mfma_f32_16x16x32_bf16(pa[0][k2], vf, o[0][nf], 0, 0, 0);
          if (act1) o[1][nf] = __builtin_amdgcn_mfma_f32_16x16x32_bf16(pa[1][k2], vf, o[1][nf], 0, 0, 0);
        }
      }
      // row-sum accumulation via ones-fragment MFMA (softmax denominator)
      #pragma unroll
      for (int k2 = 0; k2 < 2; ++k2) {
        if (act0) rs[0] = __builtin_amdgcn_mfma_f32_16x16x32_bf16(pa[0][k2], ones, rs[0], 0, 0, 0);
        if (act1) rs[1] = __builtin_amdgcn_mfma_f32_16x16x32_bf16(pa[1][k2], ones, rs[1], 0, 0, 0);
      }
      __builtin_amdgcn_s_setprio(0);
    }
  }

  #pragma unroll
  for (int mf = 0; mf < 2; ++mf) {
    const int qb0 = mf ? qband1 : qband0;
    #pragma unroll
    for (int i = 0; i < 4; ++i) {
      const float inv = 1.0f / rs[mf][i];
      const int q = qb0 + l4 * 4 + i;
      unsigned short* yr = y + (size_t)(b * T_ + q) * C_ + h * 64;
      #pragma unroll
      for (int nf = 0; nf < 4; ++nf)
        yr[nf * 16 + l15] = f2bf(o[mf][nf][i] * inv);
    }
  }
}

// ---------------- head ----------------
__global__ __launch_bounds__(256) void head_kernel(
    const float* __restrict__ lnf, const float* __restrict__ wte,
    float* __restrict__ out)
{
  __shared__ float xs[B_ * C_];
  for (int i = threadIdx.x; i < B_ * C_; i += 256) xs[i] = lnf[i];
  __syncthreads();
  const int w = threadIdx.x >> 6, lane = threadIdx.x & 63;
  const int v = blockIdx.x * 4 + w;
  if (v >= V_) return;
  const float* wv = wte + (size_t)v * C_ + lane * 12;
  float4 w0 = *(const float4*)(wv);
  float4 w1 = *(const float4*)(wv + 4);
  float4 w2 = *(const float4*)(wv + 8);
  float acc[B_];
  #pragma unroll
  for (int bb = 0; bb < B_; ++bb) {
    const float* xr = xs + bb * C_ + lane * 12;
    float4 x0 = *(const float4*)(xr);
    float4 x1 = *(const float4*)(xr + 4);
    float4 x2 = *(const float4*)(xr + 8);
    acc[bb] = w0.x * x0.x + w0.y * x0.y + w0.z * x0.z + w0.w * x0.w
            + w1.x * x1.x + w1.y * x1.y + w1.z * x1.z + w1.w * x1.w
            + w2.x * x2.x + w2.y * x2.y + w2.z * x2.z + w2.w * x2.w;
  }
  #pragma unroll
  for (int off = 32; off; off >>= 1) {
    #pragma unroll
    for (int bb = 0; bb < B_; ++bb)
      acc[bb] += __shfl_xor(acc[bb], off);
  }
  if (lane == 0) {
    #pragma unroll
    for (int bb = 0; bb < B_; ++bb)
      out[(size_t)bb * V_ + v] = acc[bb];
  }
}

// ---------------- launcher ----------------
extern "C" void kernel_launch(void* const* d_in, const int* in_sizes, int n_in,
                              void* d_out, int out_size, void* d_ws, size_t ws_size,
                              hipStream_t stream)
{
  (void)in_sizes; (void)n_in; (void)out_size; (void)ws_size;
  const int*   idx   = (const int*)d_in[0];
  const float* wte   = (const float*)d_in[1];
  const float* wpe   = (const float*)d_in[2];
  const float* ln1_g = (const float*)d_in[3];
  const float* ln1_b = (const float*)d_in[4];
  const float* w_qkv = (const float*)d_in[5];
  const float* b_qkv = (const float*)d_in[6];
  const float* w_ao  = (const float*)d_in[7];
  const float* b_ao  = (const float*)d_in[8];
  const float* ln2_g = (const float*)d_in[9];
  const float* ln2_b = (const float*)d_in[10];
  const float* w_fc  = (const float*)d_in[11];
  const float* b_fc  = (const float*)d_in[12];
  const float* w_mo  = (const float*)d_in[13];
  const float* b_mo  = (const float*)d_in[14];
  const float* lnf_g = (const float*)d_in[15];
  const float* lnf_b = (const float*)d_in[16];

  char* ws = (char*)d_ws;
  size_t off = 0;
  auto wsalloc = [&](size_t bytes) -> void* {
    void* p = ws + off;
    off += (bytes + 255) & ~(size_t)255;
    return p;
  };
  const size_t SZH = (size_t)B_ * H_ * T_ * 64;
  float* xf             = (float*)wsalloc((size_t)B_ * T_ * C_ * 4);
  unsigned short* qkv3  = (unsigned short*)wsalloc(3 * SZH * 2);
  unsigned short* a_in  = (unsigned short*)wsalloc((size_t)B_ * T_ * C_ * 2);
  unsigned short* act2  = (unsigned short*)wsalloc((size_t)B_ * T_ * 4 * C_ * 2);
  unsigned short* wbuf  = (unsigned short*)wsalloc((size_t)12 * C_ * C_ * 2);
  float* lnfb           = (float*)wsalloc((size_t)B_ * C_ * 4);

  const size_t OFF_AO = (size_t)3 * C_ * C_;
  const size_t OFF_FC = (size_t)4 * C_ * C_;
  const size_t OFF_MO = (size_t)8 * C_ * C_;
  const int MROWS = B_ * T_;

  embed_kernel<<<B_ * T_, 192, 0, stream>>>(idx, wte, wpe, xf);

  for (int l = 0; l < L_; ++l) {
    ln_kernel<false><<<B_ * T_, 256, 0, stream>>>(xf, ln1_g + l * C_, ln1_b + l * C_, a_in, nullptr);
    cvtw4_kernel<<<6912, 256, 0, stream>>>(
        w_qkv + (size_t)l * C_ * 3 * C_, w_ao + (size_t)l * C_ * C_,
        w_fc + (size_t)l * C_ * 4 * C_, w_mo + (size_t)l * 4 * C_ * C_, wbuf);
    gemm_bt<3><<<64 * 18, 256, 0, stream>>>(a_in, wbuf, b_qkv + l * 3 * C_, nullptr, qkv3, MROWS, 3 * C_, C_, 18);
    attn_kernel<<<8 * B_ * H_, 256, 0, stream>>>(qkv3, qkv3 + SZH, qkv3 + 2 * SZH, a_in);
    gemm_bt<1><<<64 * 6, 256, 0, stream>>>(a_in, wbuf + OFF_AO, b_ao + l * C_, xf, nullptr, MROWS, C_, C_, 6);
    ln_kernel<false><<<B_ * T_, 256, 0, stream>>>(xf, ln2_g + l * C_, ln2_b + l * C_, a_in, nullptr);
    gemm_bt<2><<<64 * 24, 256, 0, stream>>>(a_in, wbuf + OFF_FC, b_fc + l * 4 * C_, nullptr, act2, MROWS, 4 * C_, C_, 24);
    gemm_bt<1><<<64 * 6, 256, 0, stream>>>(act2, wbuf + OFF_MO, b_mo + l * C_, xf, nullptr, MROWS, C_, 4 * C_, 6);
  }

  ln_kernel<true><<<B_, 256, 0, stream>>>(xf, lnf_g, lnf_b, nullptr, lnfb);
  head_kernel<<<(V_ + 3) / 4, 256, 0, stream>>>(lnfb, wte, (float*)d_out);
}